// Round 1
// baseline (424.410 us; speedup 1.0000x reference)
//
#include <hip/hip_runtime.h>

#define NN   10000
#define EE   160000
#define CINC 32
#define COUTC 32
#define RRR  6
#define MMM  3
#define RM   (RRR*MMM)      // 18
#define KK   (RM*CINC)      // 576
#define EPSV 1e-8f

// ---------------- CSR build ----------------

__global__ void k_zero(int* counts) {
    int i = blockIdx.x*blockDim.x + threadIdx.x;
    if (i < NN+1) counts[i] = 0;
}

__global__ void k_hist(const int* __restrict__ edges, int* __restrict__ counts) {
    int i = blockIdx.x*blockDim.x + threadIdx.x;
    if (i < EE) atomicAdd(&counts[edges[2*i+1]], 1);
}

__global__ void k_scan(int* __restrict__ counts, int* __restrict__ cursor) {
    __shared__ int sums[1024];
    const int CH = 10;                 // 1024*10 >= 10000
    int t = threadIdx.x;
    int beg = t*CH;
    int end = beg + CH; if (end > NN) end = NN;
    int local[CH];
    int s = 0;
    for (int i = beg; i < end; ++i) { int v = counts[i]; local[i-beg] = v; s += v; }
    sums[t] = s;
    __syncthreads();
    for (int off = 1; off < 1024; off <<= 1) {
        int v = 0;
        if (t >= off) v = sums[t-off];
        __syncthreads();
        if (t >= off) sums[t] += v;
        __syncthreads();
    }
    int run = sums[t] - s;             // exclusive prefix
    for (int i = beg; i < end; ++i) { counts[i] = run; cursor[i] = run; run += local[i-beg]; }
    if (t == 1023) counts[NN] = run;   // == EE
}

__global__ void k_scatter(const int* __restrict__ edges, int* __restrict__ cursor,
                          int* __restrict__ sorted_eid) {
    int i = blockIdx.x*blockDim.x + threadIdx.x;
    if (i < EE) {
        int tgt = edges[2*i+1];
        int pos = atomicAdd(&cursor[tgt], 1);
        sorted_eid[pos] = i;
    }
}

// ---------------- phased weights ----------------

__global__ void k_wc(const float* __restrict__ w1, const float* __restrict__ off1,
                     const float* __restrict__ w2, const float* __restrict__ off2,
                     float2* __restrict__ Wc1, float2* __restrict__ Wc2) {
    int f = blockIdx.x*blockDim.x + threadIdx.x;
    if (f >= KK*COUTC) return;
    int d = f % COUTC;
    int c = (f / COUTC) % CINC;
    float o1 = off1[c*COUTC + d];
    float o2 = off2[c*COUTC + d];
    float s1, c1, s2, c2;
    __sincosf(o1, &s1, &c1);
    __sincosf(o2, &s2, &c2);
    // use precise variants to be safe on accuracy budget
    s1 = sinf(o1); c1 = cosf(o1);
    s2 = sinf(o2); c2 = cosf(o2);
    Wc1[f] = make_float2(w1[f]*c1, w1[f]*s1);
    Wc2[f] = make_float2(w2[f]*c2, w2[f]*s2);
}

// ---------------- fused conv (+optional residual) + tangent nonlin ----------------

template<bool FINAL>
__global__ void k_conv(const float2* __restrict__ xin,      // (NN,32) complex input
                       const int*  __restrict__ offsets,    // (NN+1)
                       const int*  __restrict__ sorted_eid, // (EE)
                       const int*  __restrict__ edges,      // (EE,2)
                       const float2* __restrict__ stenc,    // (EE,18) complex
                       const float2* __restrict__ Wc,       // (KK,32) complex
                       const float* __restrict__ bias,      // (32)
                       const float2* __restrict__ xres,     // (NN,32) original xc (FINAL)
                       const float2* __restrict__ resw,     // (32,32) complex (FINAL)
                       float2* __restrict__ out)            // (NN,32) complex
{
    __shared__ float2 agg[KK];
    __shared__ float2 part[256];
    int n = blockIdx.x;
    int t = threadIdx.x;

    float2 acc0 = make_float2(0.f, 0.f);
    float2 acc1 = make_float2(0.f, 0.f);
    float2 acc2 = make_float2(0.f, 0.f);

    int k0 = t, k1 = t + 256, k2 = t + 512;
    int rm0 = k0 >> 5, c0 = k0 & 31;
    int rm1 = k1 >> 5, c1 = k1 & 31;
    int rm2 = k2 >> 5, c2 = k2 & 31;   // valid only for t < 64
    bool has2 = (t < KK - 512);

    int beg = offsets[n], end = offsets[n+1];
    for (int e = beg; e < end; ++e) {
        int eid = sorted_eid[e];
        int src = edges[2*eid];
        const float2* st = stenc + (size_t)eid * RM;
        const float2* xv = xin  + (size_t)src * CINC;
        float2 s, x;
        s = st[rm0]; x = xv[c0];
        acc0.x += s.x*x.x - s.y*x.y;  acc0.y += s.x*x.y + s.y*x.x;
        s = st[rm1]; x = xv[c1];
        acc1.x += s.x*x.x - s.y*x.y;  acc1.y += s.x*x.y + s.y*x.x;
        if (has2) {
            s = st[rm2]; x = xv[c2];
            acc2.x += s.x*x.x - s.y*x.y;  acc2.y += s.x*x.y + s.y*x.x;
        }
    }
    agg[k0] = acc0;
    agg[k1] = acc1;
    if (has2) agg[k2] = acc2;
    __syncthreads();

    // einsum: out[d] = sum_k agg[k] * Wc[k,d];  8 chunks of 72 k's
    int d = t & 31;
    int chunk = t >> 5;
    float2 p = make_float2(0.f, 0.f);
    int kb = chunk * 72;
    #pragma unroll 8
    for (int q = 0; q < 72; ++q) {
        float2 a = agg[kb + q];
        float2 w = Wc[(kb + q) * COUTC + d];
        p.x += a.x*w.x - a.y*w.y;
        p.y += a.x*w.y + a.y*w.x;
    }
    part[t] = p;
    __syncthreads();

    if (t < 32) {
        float2 hv = make_float2(0.f, 0.f);
        #pragma unroll
        for (int ch = 0; ch < 8; ++ch) {
            hv.x += part[ch*32 + t].x;
            hv.y += part[ch*32 + t].y;
        }
        if (FINAL) {
            const float2* xr = xres + (size_t)n * CINC;
            #pragma unroll
            for (int c = 0; c < CINC; ++c) {
                float2 xv = xr[c];
                float2 w = resw[c*COUTC + t];
                hv.x += xv.x*w.x - xv.y*w.y;
                hv.y += xv.x*w.y + xv.y*w.x;
            }
        }
        float mag = sqrtf(hv.x*hv.x + hv.y*hv.y);
        float num = mag + bias[t]; if (num < 0.f) num = 0.f;
        float den = (mag > EPSV) ? mag : EPSV;
        float f = num / den;
        out[(size_t)n*COUTC + t] = make_float2(f*hv.x, f*hv.y);
    }
}

// ---------------- launch ----------------

extern "C" void kernel_launch(void* const* d_in, const int* in_sizes, int n_in,
                              void* d_out, int out_size, void* d_ws, size_t ws_size,
                              hipStream_t stream) {
    const float2* xc   = (const float2*)d_in[0];   // (N,32,2) -> complex
    const int*   edges = (const int*)  d_in[1];    // (E,2)
    const float2* stenc= (const float2*)d_in[2];   // (E,6,3,2) -> (E,18) complex
    const float* w1    = (const float*)d_in[3];
    const float* off1  = (const float*)d_in[4];
    const float* b1    = (const float*)d_in[5];
    const float* w2    = (const float*)d_in[6];
    const float* off2  = (const float*)d_in[7];
    const float* b2    = (const float*)d_in[8];
    const float2* resw = (const float2*)d_in[9];   // (32,32) complex
    float2* out = (float2*)d_out;

    char* ws = (char*)d_ws;
    size_t o = 0;
    auto alloc = [&](size_t bytes) {
        o = (o + 255) & ~(size_t)255;
        size_t r = o; o += bytes; return r;
    };
    int*    counts     = (int*)   (ws + alloc((NN+1)*sizeof(int)));
    int*    cursor     = (int*)   (ws + alloc(NN*sizeof(int)));
    int*    sorted_eid = (int*)   (ws + alloc(EE*sizeof(int)));
    float2* Wc1        = (float2*)(ws + alloc((size_t)KK*COUTC*sizeof(float2)));
    float2* Wc2        = (float2*)(ws + alloc((size_t)KK*COUTC*sizeof(float2)));
    float2* h          = (float2*)(ws + alloc((size_t)NN*COUTC*sizeof(float2)));
    (void)ws_size; (void)in_sizes; (void)n_in; (void)out_size;

    k_zero   <<<(NN+1+255)/256, 256, 0, stream>>>(counts);
    k_hist   <<<(EE+255)/256,   256, 0, stream>>>(edges, counts);
    k_scan   <<<1, 1024, 0, stream>>>(counts, cursor);
    k_scatter<<<(EE+255)/256,   256, 0, stream>>>(edges, cursor, sorted_eid);
    k_wc     <<<(KK*COUTC+255)/256, 256, 0, stream>>>(w1, off1, w2, off2, Wc1, Wc2);

    k_conv<false><<<NN, 256, 0, stream>>>(xc, counts, sorted_eid, edges, stenc, Wc1, b1,
                                          nullptr, nullptr, h);
    k_conv<true> <<<NN, 256, 0, stream>>>(h, counts, sorted_eid, edges, stenc, Wc2, b2,
                                          xc, resw, out);
}

// Round 2
// 271.785 us; speedup vs baseline: 1.5616x; 1.5616x over previous
//
#include <hip/hip_runtime.h>

#define NN   10000
#define EE   160000
#define CINC 32
#define COUTC 32
#define RRR  6
#define MMM  3
#define RM   (RRR*MMM)      // 18
#define KK   (RM*CINC)      // 576
#define NPB  4              // nodes per block in k_conv
#define EPSV 1e-8f

// ---------------- CSR build ----------------

__global__ void k_zero(int* counts) {
    int i = blockIdx.x*blockDim.x + threadIdx.x;
    if (i < NN+1) counts[i] = 0;
}

__global__ void k_hist(const int* __restrict__ edges, int* __restrict__ counts) {
    int i = blockIdx.x*blockDim.x + threadIdx.x;
    if (i < EE) atomicAdd(&counts[edges[2*i+1]], 1);
}

__global__ void k_scan(int* __restrict__ counts, int* __restrict__ cursor) {
    __shared__ int sums[1024];
    const int CH = 10;                 // 1024*10 >= 10000
    int t = threadIdx.x;
    int beg = t*CH;
    int end = beg + CH; if (end > NN) end = NN;
    int local[CH];
    int s = 0;
    for (int i = beg; i < end; ++i) { int v = counts[i]; local[i-beg] = v; s += v; }
    sums[t] = s;
    __syncthreads();
    for (int off = 1; off < 1024; off <<= 1) {
        int v = 0;
        if (t >= off) v = sums[t-off];
        __syncthreads();
        if (t >= off) sums[t] += v;
        __syncthreads();
    }
    int run = sums[t] - s;             // exclusive prefix
    for (int i = beg; i < end; ++i) { counts[i] = run; cursor[i] = run; run += local[i-beg]; }
    if (t == 1023) counts[NN] = run;   // == EE
}

// store (src, eid) pairs sorted by target -> single 8B load in conv edge loop
__global__ void k_scatter(const int* __restrict__ edges, int* __restrict__ cursor,
                          int2* __restrict__ srcrid) {
    int i = blockIdx.x*blockDim.x + threadIdx.x;
    if (i < EE) {
        int src = edges[2*i];
        int tgt = edges[2*i+1];
        int pos = atomicAdd(&cursor[tgt], 1);
        srcrid[pos] = make_int2(src, i);
    }
}

// ---------------- phased weights ----------------

__global__ void k_wc(const float* __restrict__ w1, const float* __restrict__ off1,
                     const float* __restrict__ w2, const float* __restrict__ off2,
                     float2* __restrict__ Wc1, float2* __restrict__ Wc2) {
    int f = blockIdx.x*blockDim.x + threadIdx.x;
    if (f >= KK*COUTC) return;
    int d = f % COUTC;
    int c = (f / COUTC) % CINC;
    float o1 = off1[c*COUTC + d];
    float o2 = off2[c*COUTC + d];
    float s1 = sinf(o1), c1 = cosf(o1);
    float s2 = sinf(o2), c2 = cosf(o2);
    Wc1[f] = make_float2(w1[f]*c1, w1[f]*s1);
    Wc2[f] = make_float2(w2[f]*c2, w2[f]*s2);
}

// ---------------- fused conv (+optional residual) + tangent nonlin ----------------
// 4 nodes per block. Edge phase: 4 groups x 64 threads, thread owns 9 rm's for
// one c lane (9 independent FMA chains). Einsum: each Wc load feeds 4 nodes.

template<bool FINAL>
__global__ void __launch_bounds__(256)
k_conv(const float2* __restrict__ xin,      // (NN,32) complex input
       const int*  __restrict__ offsets,    // (NN+1)
       const int2* __restrict__ srcrid,     // (EE) (src,eid) sorted by target
       const float2* __restrict__ stenc,    // (EE,18) complex
       const float2* __restrict__ Wc,       // (KK,32) complex
       const float* __restrict__ bias,      // (32)
       const float2* __restrict__ xres,     // (NN,32) original xc (FINAL)
       const float2* __restrict__ resw,     // (32,32) complex (FINAL)
       float2* __restrict__ out)            // (NN,32) complex
{
    __shared__ float2 agg[NPB*KK];          // 18432 B
    __shared__ float2 part[8*32*NPB];       // part[j*256 + chunk*32 + d], 8192 B
    int t = threadIdx.x;

    // ---- edge aggregation ----
    {
        int g = t >> 6;                     // group = node slot 0..3
        int l = t & 63;
        int n = blockIdx.x*NPB + g;
        int c = l & 31;
        int rm0 = (l >> 5) * 9;             // 0 or 9
        float2 acc[9];
        #pragma unroll
        for (int j = 0; j < 9; ++j) acc[j] = make_float2(0.f, 0.f);

        int beg = offsets[n], end = offsets[n+1];
        for (int e = beg; e < end; ++e) {
            int2 se = srcrid[e];
            const float2* st = stenc + (size_t)se.y * RM + rm0;
            float2 xv = xin[(size_t)se.x * CINC + c];
            #pragma unroll
            for (int j = 0; j < 9; ++j) {
                float2 s = st[j];
                acc[j].x = fmaf(s.x, xv.x, fmaf(-s.y, xv.y, acc[j].x));
                acc[j].y = fmaf(s.x, xv.y, fmaf( s.y, xv.x, acc[j].y));
            }
        }
        #pragma unroll
        for (int j = 0; j < 9; ++j)
            agg[g*KK + c + 32*(rm0 + j)] = acc[j];
    }
    __syncthreads();

    // ---- einsum: out[n,d] = sum_k agg[n,k] * Wc[k,d] ----
    {
        int d = t & 31;
        int chunk = t >> 5;                 // 8 chunks of 72 k's
        int kb = chunk * 72;
        float2 p[NPB];
        #pragma unroll
        for (int j = 0; j < NPB; ++j) p[j] = make_float2(0.f, 0.f);
        #pragma unroll 4
        for (int q = 0; q < 72; ++q) {
            float2 w = Wc[(size_t)(kb + q) * COUTC + d];
            #pragma unroll
            for (int j = 0; j < NPB; ++j) {
                float2 a = agg[j*KK + kb + q];
                p[j].x += a.x*w.x - a.y*w.y;
                p[j].y += a.x*w.y + a.y*w.x;
            }
        }
        #pragma unroll
        for (int j = 0; j < NPB; ++j) part[j*256 + t] = p[j];
    }
    __syncthreads();

    // ---- reduce chunks, residual, nonlinearity ----
    if (t < NPB*32) {
        int j = t >> 5, d = t & 31;
        int n = blockIdx.x*NPB + j;
        float2 hv = make_float2(0.f, 0.f);
        #pragma unroll
        for (int ch = 0; ch < 8; ++ch) {
            float2 v = part[j*256 + ch*32 + d];
            hv.x += v.x; hv.y += v.y;
        }
        if (FINAL) {
            const float2* xr = xres + (size_t)n * CINC;
            #pragma unroll
            for (int c = 0; c < CINC; ++c) {
                float2 xv = xr[c];
                float2 w = resw[c*COUTC + d];
                hv.x += xv.x*w.x - xv.y*w.y;
                hv.y += xv.x*w.y + xv.y*w.x;
            }
        }
        float mag = sqrtf(hv.x*hv.x + hv.y*hv.y);
        float num = mag + bias[d]; if (num < 0.f) num = 0.f;
        float den = (mag > EPSV) ? mag : EPSV;
        float f = num / den;
        out[(size_t)n*COUTC + d] = make_float2(f*hv.x, f*hv.y);
    }
}

// ---------------- launch ----------------

extern "C" void kernel_launch(void* const* d_in, const int* in_sizes, int n_in,
                              void* d_out, int out_size, void* d_ws, size_t ws_size,
                              hipStream_t stream) {
    const float2* xc   = (const float2*)d_in[0];   // (N,32,2) -> complex
    const int*   edges = (const int*)  d_in[1];    // (E,2)
    const float2* stenc= (const float2*)d_in[2];   // (E,6,3,2) -> (E,18) complex
    const float* w1    = (const float*)d_in[3];
    const float* off1  = (const float*)d_in[4];
    const float* b1    = (const float*)d_in[5];
    const float* w2    = (const float*)d_in[6];
    const float* off2  = (const float*)d_in[7];
    const float* b2    = (const float*)d_in[8];
    const float2* resw = (const float2*)d_in[9];   // (32,32) complex
    float2* out = (float2*)d_out;

    char* ws = (char*)d_ws;
    size_t o = 0;
    auto alloc = [&](size_t bytes) {
        o = (o + 255) & ~(size_t)255;
        size_t r = o; o += bytes; return r;
    };
    int*    counts = (int*)   (ws + alloc((NN+1)*sizeof(int)));
    int*    cursor = (int*)   (ws + alloc(NN*sizeof(int)));
    int2*   srcrid = (int2*)  (ws + alloc(EE*sizeof(int2)));
    float2* Wc1    = (float2*)(ws + alloc((size_t)KK*COUTC*sizeof(float2)));
    float2* Wc2    = (float2*)(ws + alloc((size_t)KK*COUTC*sizeof(float2)));
    float2* h      = (float2*)(ws + alloc((size_t)NN*COUTC*sizeof(float2)));
    (void)ws_size; (void)in_sizes; (void)n_in; (void)out_size;

    k_zero   <<<(NN+1+255)/256, 256, 0, stream>>>(counts);
    k_hist   <<<(EE+255)/256,   256, 0, stream>>>(edges, counts);
    k_scan   <<<1, 1024, 0, stream>>>(counts, cursor);
    k_scatter<<<(EE+255)/256,   256, 0, stream>>>(edges, cursor, srcrid);
    k_wc     <<<(KK*COUTC+255)/256, 256, 0, stream>>>(w1, off1, w2, off2, Wc1, Wc2);

    k_conv<false><<<NN/NPB, 256, 0, stream>>>(xc, counts, srcrid, stenc, Wc1, b1,
                                              nullptr, nullptr, h);
    k_conv<true> <<<NN/NPB, 256, 0, stream>>>(h, counts, srcrid, stenc, Wc2, b2,
                                              xc, resw, out);
}

// Round 3
// 264.766 us; speedup vs baseline: 1.6030x; 1.0265x over previous
//
#include <hip/hip_runtime.h>

#define NN   10000
#define EE   160000
#define CINC 32
#define COUTC 32
#define RRR  6
#define MMM  3
#define RM   (RRR*MMM)      // 18
#define KK   (RM*CINC)      // 576
#define NPB  4              // nodes per block in k_conv
#define PART_STRIDE 132     // 4*32 + 4 pad (float2 units) per chunk
#define EPSV 1e-8f

// ---------------- prep: zero counts + phased weights (merged) ----------------

__global__ void k_prep(int* __restrict__ counts,
                       const float* __restrict__ w1, const float* __restrict__ off1,
                       const float* __restrict__ w2, const float* __restrict__ off2,
                       float2* __restrict__ Wc1, float2* __restrict__ Wc2) {
    int i = blockIdx.x*blockDim.x + threadIdx.x;
    if (i < NN+1) counts[i] = 0;
    if (i < KK*COUTC) {
        int d = i % COUTC;
        int c = (i / COUTC) % CINC;
        float o1 = off1[c*COUTC + d];
        float o2 = off2[c*COUTC + d];
        float s1 = sinf(o1), c1 = cosf(o1);
        float s2 = sinf(o2), c2 = cosf(o2);
        Wc1[i] = make_float2(w1[i]*c1, w1[i]*s1);
        Wc2[i] = make_float2(w2[i]*c2, w2[i]*s2);
    }
}

__global__ void k_hist(const int* __restrict__ edges, int* __restrict__ counts) {
    int i = blockIdx.x*blockDim.x + threadIdx.x;
    if (i < EE) atomicAdd(&counts[edges[2*i+1]], 1);
}

__global__ void k_scan(int* __restrict__ counts, int* __restrict__ cursor) {
    __shared__ int sums[1024];
    const int CH = 10;                 // 1024*10 >= 10000
    int t = threadIdx.x;
    int beg = t*CH;
    int end = beg + CH; if (end > NN) end = NN;
    int local[CH];
    int s = 0;
    for (int i = beg; i < end; ++i) { int v = counts[i]; local[i-beg] = v; s += v; }
    sums[t] = s;
    __syncthreads();
    for (int off = 1; off < 1024; off <<= 1) {
        int v = 0;
        if (t >= off) v = sums[t-off];
        __syncthreads();
        if (t >= off) sums[t] += v;
        __syncthreads();
    }
    int run = sums[t] - s;             // exclusive prefix
    for (int i = beg; i < end; ++i) { counts[i] = run; cursor[i] = run; run += local[i-beg]; }
    if (t == 1023) counts[NN] = run;   // == EE
}

__global__ void k_scatter(const int* __restrict__ edges, int* __restrict__ cursor,
                          int2* __restrict__ srcrid) {
    int i = blockIdx.x*blockDim.x + threadIdx.x;
    if (i < EE) {
        int src = edges[2*i];
        int tgt = edges[2*i+1];
        int pos = atomicAdd(&cursor[tgt], 1);
        srcrid[pos] = make_int2(src, i);
    }
}

// ---------------- fused conv (+optional residual) + tangent nonlin ----------------
// 4 nodes/block, 1 wave per node. Edge phase: lane owns c=l&31 and ALL 18 rm;
// the two 32-lane halves process alternate edges (2 edges in flight),
// stencil row loaded as 9 x float4 (144B, 16B-aligned), srcrid prefetched.
// Einsum: lane owns a d-pair (float4 Wc loads), 16 chunks x 36 k.
// `part` aliases the agg LDS region (reads complete before overwrite).

template<bool FINAL>
__global__ void __launch_bounds__(256)
k_conv(const float2* __restrict__ xin,      // (NN,32) complex input
       const int*  __restrict__ offsets,    // (NN+1)
       const int2* __restrict__ srcrid,     // (EE) (src,eid) sorted by target
       const float2* __restrict__ stenc,    // (EE,18) complex
       const float2* __restrict__ Wc,       // (KK,32) complex
       const float* __restrict__ bias,      // (32)
       const float2* __restrict__ xres,     // (NN,32) original xc (FINAL)
       const float2* __restrict__ resw,     // (32,32) complex (FINAL)
       float2* __restrict__ out)            // (NN,32) complex
{
    __shared__ float2 smem[NPB*KK];         // 18432 B; agg then reused as part
    float2* agg = smem;
    int t = threadIdx.x;

    // ---- edge aggregation ----
    {
        int g = t >> 6;                     // node slot 0..3 (one wave each)
        int l = t & 63;
        int n = blockIdx.x*NPB + g;
        int c = l & 31;
        int h = l >> 5;                     // half: which alternate edges
        float2 acc[RM];
        #pragma unroll
        for (int k = 0; k < RM; ++k) acc[k] = make_float2(0.f, 0.f);

        int beg = offsets[n], end = offsets[n+1];
        int deg = end - beg;
        int iters = (deg + 1) >> 1;
        int e = beg + h;
        int2 se = make_int2(0, 0);
        bool v = (e < end);
        if (v) se = srcrid[e];
        for (int i = 0; i < iters; ++i) {
            int en = e + 2;
            bool vn = (en < end);
            int2 sen = make_int2(0, 0);
            if (vn) sen = srcrid[en];       // prefetch next iteration's pair
            if (v) {
                const float4* st4 = (const float4*)(stenc + (size_t)se.y * RM);
                float2 xv = xin[(size_t)se.x * CINC + c];
                #pragma unroll
                for (int j = 0; j < 9; ++j) {
                    float4 s = st4[j];
                    acc[2*j].x   = fmaf(s.x, xv.x, fmaf(-s.y, xv.y, acc[2*j].x));
                    acc[2*j].y   = fmaf(s.x, xv.y, fmaf( s.y, xv.x, acc[2*j].y));
                    acc[2*j+1].x = fmaf(s.z, xv.x, fmaf(-s.w, xv.y, acc[2*j+1].x));
                    acc[2*j+1].y = fmaf(s.z, xv.y, fmaf( s.w, xv.x, acc[2*j+1].y));
                }
            }
            se = sen; v = vn; e = en;
        }
        // merge the two halves (half1 -> half0)
        #pragma unroll
        for (int k = 0; k < RM; ++k) {
            acc[k].x += __shfl_down(acc[k].x, 32, 64);
            acc[k].y += __shfl_down(acc[k].y, 32, 64);
        }
        if (h == 0) {
            #pragma unroll
            for (int k = 0; k < RM; ++k)
                agg[g*KK + k*32 + c] = acc[k];
        }
    }
    __syncthreads();

    // ---- einsum: out[n,d] = sum_k agg[n,k] * Wc[k,d] ----
    int ch = t >> 4;                        // 16 chunks of 36 k's
    int dp = (t & 15) * 2;                  // d-pair base
    int kb = ch * 36;
    float2 p0[NPB], p1[NPB];
    #pragma unroll
    for (int j = 0; j < NPB; ++j) { p0[j] = make_float2(0.f,0.f); p1[j] = make_float2(0.f,0.f); }
    #pragma unroll 4
    for (int q = 0; q < 36; ++q) {
        float4 w = *(const float4*)(Wc + (size_t)(kb + q) * COUTC + dp);
        #pragma unroll
        for (int j = 0; j < NPB; ++j) {
            float2 a = agg[j*KK + kb + q];
            p0[j].x += a.x*w.x - a.y*w.y;
            p0[j].y += a.x*w.y + a.y*w.x;
            p1[j].x += a.x*w.z - a.y*w.w;
            p1[j].y += a.x*w.w + a.y*w.z;
        }
    }
    __syncthreads();                        // all agg reads done; reuse as part
    float2* part = smem;                    // [16][PART_STRIDE] : [ch][j*32+d]
    #pragma unroll
    for (int j = 0; j < NPB; ++j)
        *(float4*)&part[(size_t)ch*PART_STRIDE + j*32 + dp] =
            make_float4(p0[j].x, p0[j].y, p1[j].x, p1[j].y);
    __syncthreads();

    // ---- reduce chunks, residual, nonlinearity ----
    if (t < NPB*32) {
        int j = t >> 5, d = t & 31;
        int n = blockIdx.x*NPB + j;
        float2 hv = make_float2(0.f, 0.f);
        #pragma unroll
        for (int c2 = 0; c2 < 16; ++c2) {
            float2 vv = part[(size_t)c2*PART_STRIDE + j*32 + d];
            hv.x += vv.x; hv.y += vv.y;
        }
        if (FINAL) {
            const float2* xr = xres + (size_t)n * CINC;
            #pragma unroll
            for (int c = 0; c < CINC; ++c) {
                float2 xv = xr[c];
                float2 w = resw[c*COUTC + d];
                hv.x += xv.x*w.x - xv.y*w.y;
                hv.y += xv.x*w.y + xv.y*w.x;
            }
        }
        float mag = sqrtf(hv.x*hv.x + hv.y*hv.y);
        float num = mag + bias[d]; if (num < 0.f) num = 0.f;
        float den = (mag > EPSV) ? mag : EPSV;
        float f = num / den;
        out[(size_t)n*COUTC + d] = make_float2(f*hv.x, f*hv.y);
    }
}

// ---------------- launch ----------------

extern "C" void kernel_launch(void* const* d_in, const int* in_sizes, int n_in,
                              void* d_out, int out_size, void* d_ws, size_t ws_size,
                              hipStream_t stream) {
    const float2* xc   = (const float2*)d_in[0];   // (N,32,2) -> complex
    const int*   edges = (const int*)  d_in[1];    // (E,2)
    const float2* stenc= (const float2*)d_in[2];   // (E,6,3,2) -> (E,18) complex
    const float* w1    = (const float*)d_in[3];
    const float* off1  = (const float*)d_in[4];
    const float* b1    = (const float*)d_in[5];
    const float* w2    = (const float*)d_in[6];
    const float* off2  = (const float*)d_in[7];
    const float* b2    = (const float*)d_in[8];
    const float2* resw = (const float2*)d_in[9];   // (32,32) complex
    float2* out = (float2*)d_out;

    char* ws = (char*)d_ws;
    size_t o = 0;
    auto alloc = [&](size_t bytes) {
        o = (o + 255) & ~(size_t)255;
        size_t r = o; o += bytes; return r;
    };
    int*    counts = (int*)   (ws + alloc((NN+1)*sizeof(int)));
    int*    cursor = (int*)   (ws + alloc(NN*sizeof(int)));
    int2*   srcrid = (int2*)  (ws + alloc(EE*sizeof(int2)));
    float2* Wc1    = (float2*)(ws + alloc((size_t)KK*COUTC*sizeof(float2)));
    float2* Wc2    = (float2*)(ws + alloc((size_t)KK*COUTC*sizeof(float2)));
    float2* h      = (float2*)(ws + alloc((size_t)NN*COUTC*sizeof(float2)));
    (void)ws_size; (void)in_sizes; (void)n_in; (void)out_size;

    int prep_n = (KK*COUTC > NN+1) ? KK*COUTC : NN+1;
    k_prep   <<<(prep_n+255)/256, 256, 0, stream>>>(counts, w1, off1, w2, off2, Wc1, Wc2);
    k_hist   <<<(EE+255)/256,   256, 0, stream>>>(edges, counts);
    k_scan   <<<1, 1024, 0, stream>>>(counts, cursor);
    k_scatter<<<(EE+255)/256,   256, 0, stream>>>(edges, cursor, srcrid);

    k_conv<false><<<NN/NPB, 256, 0, stream>>>(xc, counts, srcrid, stenc, Wc1, b1,
                                              nullptr, nullptr, h);
    k_conv<true> <<<NN/NPB, 256, 0, stream>>>(h, counts, srcrid, stenc, Wc2, b2,
                                              xc, resw, out);
}